// Round 8
// baseline (317.586 us; speedup 1.0000x reference)
//
#include <hip/hip_runtime.h>
#include <hip/hip_bf16.h>
#include <stdint.h>
#include <cmath>

// IDXST_IDCT on MI355X: y = S · x · C^T with
//   C[v,q] = cos(pi*q*(2v+1)/(2N)),  S[u,p] = sin(pi*p*(2u+1)/(2M))
// Butterfly halves GEMM FLOPs (dual E/O accumulators, fused epilogue).
// R14: R10's exact structure/layout/schedule, but 8 waves per 128x128
// block (512 thr, 64x32 wave tiles) -> 16 waves/CU (4/SIMD), 2x the
// latency hiding. R10 was latency-bound: nothing saturated (MFMA ~620
// cyc/SIMD, LDS ~2000 cyc of 5950 cyc/iter-pair, HBM 1.8 TB/s) at 19%
// occupancy. LDS stays 64 KB (2 blocks/CU); staging granule stays the
// full 128-B row (R11+R13 both proved 64-B granule => ~2x HBM overfetch).
// Counted waits scale: stage = 4 GLL/wave -> vmcnt(4); parity = 12
// ds_reads -> lgkm(6) -> 8 MFMA -> lgkm(0) -> 8 MFMA (setprio).
// XCD swizzle upgraded to 8x8 chunks (64 concurrent blocks/XCD form an
// 8x8 tile -> 16 panels live/XCD -> better L2 hit -> lower load latency).
// K-order/acc chain bit-identical to R10 -> absmax must stay 64.0.
// 3 dispatches total: prep, F1 (GEMM+bfly1+deint), F2 (GEMM+bfly2).

typedef __attribute__((ext_vector_type(4))) float f32x4;
typedef __attribute__((ext_vector_type(8))) unsigned short u16x8;
typedef __attribute__((ext_vector_type(8))) __bf16 bf16x8;

__device__ __forceinline__ unsigned short f2bf(float f) {
  union { float f; unsigned u; } v; v.f = f;
  unsigned u = v.u + 0x7fffu + ((v.u >> 16) & 1u);  // RNE
  return (unsigned short)(u >> 16);
}

// ---- gen device helper: half transform matrices [L/2 x L/2] bf16 ----
__device__ __forceinline__ void gen_half(int idx, u16x8* Pe, u16x8* Po,
                                         int isSin, int jshift, int jmask,
                                         unsigned mask4L, float sc) {
  int i = idx >> jshift;           // row
  int jb = (idx & jmask) * 8;      // first col
  unsigned tp = 2u * (unsigned)i + 1u;
  unsigned re = (2u * (unsigned)jb * tp) & mask4L;
  unsigned ro = (re + tp) & mask4L;
  unsigned step = (2u * tp) & mask4L;
  u16x8 pe, po;
#pragma unroll
  for (int t = 0; t < 8; t++) {
    float se_, ce_, so_, co_;
    __sincosf((float)re * sc, &se_, &ce_);
    __sincosf((float)ro * sc, &so_, &co_);
    pe[t] = f2bf(isSin ? se_ : ce_);
    po[t] = f2bf(isSin ? so_ : co_);
    re = (re + step) & mask4L;
    ro = (ro + step) & mask4L;
  }
  Pe[idx] = pe;
  Po[idx] = po;
}

// ---- single prep dispatch: convert+deint | gen Ce/Co | gen Se/So ----
__global__ void prep_kernel(const f32x4* __restrict__ x, u16x8* __restrict__ xe,
                            u16x8* __restrict__ xo, u16x8* __restrict__ Ce,
                            u16x8* __restrict__ Co, u16x8* __restrict__ Se,
                            u16x8* __restrict__ So, int nConvBlocks,
                            int nGenNBlocks, int jshiftN, int jmaskN,
                            unsigned mask4N, float scN, int jshiftM, int jmaskM,
                            unsigned mask4M, float scM) {
  int b = blockIdx.x;
  if (b < nConvBlocks) {
    int idx = b * 256 + threadIdx.x;
    f32x4 a = x[4 * idx], bb = x[4 * idx + 1], c = x[4 * idx + 2],
          d = x[4 * idx + 3];
    u16x8 e, o;
    e[0] = f2bf(a[0]);  o[0] = f2bf(a[1]);  e[1] = f2bf(a[2]);  o[1] = f2bf(a[3]);
    e[2] = f2bf(bb[0]); o[2] = f2bf(bb[1]); e[3] = f2bf(bb[2]); o[3] = f2bf(bb[3]);
    e[4] = f2bf(c[0]);  o[4] = f2bf(c[1]);  e[5] = f2bf(c[2]);  o[5] = f2bf(c[3]);
    e[6] = f2bf(d[0]);  o[6] = f2bf(d[1]);  e[7] = f2bf(d[2]);  o[7] = f2bf(d[3]);
    xe[idx] = e;
    xo[idx] = o;
  } else if (b < nConvBlocks + nGenNBlocks) {
    int idx = (b - nConvBlocks) * 256 + threadIdx.x;
    gen_half(idx, Ce, Co, 0, jshiftN, jmaskN, mask4N, scN);
  } else {
    int idx = (b - nConvBlocks - nGenNBlocks) * 256 + threadIdx.x;
    gen_half(idx, Se, So, 1, jshiftM, jmaskM, mask4M, scM);
  }
}

#define LGKM6()                                             \
  do {                                                      \
    asm volatile("s_waitcnt lgkmcnt(6)" ::: "memory");      \
    __builtin_amdgcn_sched_barrier(0);                      \
  } while (0)
#define LGKM0()                                             \
  do {                                                      \
    asm volatile("s_waitcnt lgkmcnt(0)" ::: "memory");      \
    __builtin_amdgcn_sched_barrier(0);                      \
  } while (0)
#define VMCNT4()                                            \
  do {                                                      \
    asm volatile("s_waitcnt vmcnt(4)" ::: "memory");        \
    __builtin_amdgcn_sched_barrier(0);                      \
  } while (0)
#define VMCNT0()                                            \
  do {                                                      \
    asm volatile("s_waitcnt vmcnt(0)" ::: "memory");        \
    __builtin_amdgcn_sched_barrier(0);                      \
  } while (0)
#define BAR() __builtin_amdgcn_s_barrier()

// ---- fused dual bt-GEMM + butterfly epilogue, counted-wait pipeline ----
// accE[m,n] = sum_k Ae[m,k]*Be[n,k]; accO likewise with Ao/Bo.
// BM=BN=128, BK=64, 512 threads (8 waves of 64x32; 2m x 4n), 2 blocks/CU.
// LDS: elem (row,col) at row*64 + ((col/8)^(row&7))*8 + col%8; staging lane l
// sources global col ((l&7)^(l>>3))*8 so dst stays wave-uniform-base+lane*16.
// STAGE==1 (m=v, n=p): (p&1?out1:out0)[v, p>>1] = E+O;
//                      [...][Lfull-1-v, p>>1]   = E-O   (bf16)
// STAGE==2 (m=u, n=v): y[u,v] = E+O; y[Lfull-1-u,v] = O-E  (fp32, out0)
template <int STAGE>
__global__ __launch_bounds__(512, 2) void fused_gemm_kernel(
    const unsigned short* __restrict__ Ae,
    const unsigned short* __restrict__ Ao,
    const unsigned short* __restrict__ Be,
    const unsigned short* __restrict__ Bo,
    unsigned short* __restrict__ out0, unsigned short* __restrict__ out1,
    int outStride, int K, int Lfull) {
  __shared__ unsigned short AsE[128 * 64];
  __shared__ unsigned short BsE[128 * 64];
  __shared__ unsigned short AsO[128 * 64];
  __shared__ unsigned short BsO[128 * 64];

  const int tid = threadIdx.x;

  // XCD-aware swizzle. Preferred: 8x8 block chunks per XCD (each XCD's 64
  // concurrent blocks form an 8x8 (x,y) tile -> 8 A-panels + 8 B-panels
  // live per XCD-L2). Requires gx%8==0, gy%8==0, (gx/8)*(gy/8)==8
  // (true for our 32x16 grid). Fallback: strip swizzle.
  int bx = blockIdx.x, by = blockIdx.y;
  {
    const int gx = gridDim.x, gy = gridDim.y;
    const int lin = by * gx + bx;
    if ((gx % 8) == 0 && (gy % 8) == 0 && ((gx >> 3) * (gy >> 3)) == 8) {
      const int xcd = lin & 7, idx = lin >> 3;
      const int spx = gx >> 3;  // supertiles along x
      const int sx = xcd % spx, sy = xcd / spx;
      bx = sx * 8 + (idx & 7);
      by = sy * 8 + (idx >> 3);
    } else {
      const int nwg = gx * gy;
      if ((nwg & 7) == 0) {
        const int swb = (lin & 7) * (nwg >> 3) + (lin >> 3);
        bx = swb % gx;
        by = swb / gx;
      }
    }
  }
  const int m0 = by * 128;
  const int n0 = bx * 128;

  const int wave = tid >> 6;
  const int lane = tid & 63;
  const int wm = (wave & 1) * 64;   // 2 m-waves
  const int wn = (wave >> 1) * 32;  // 4 n-waves
  const int l16 = lane & 15;
  const int quad = lane >> 4;
  const int swz = (quad ^ (l16 & 7)) * 8;  // frag col swizzle, k-half 0

  // staging: chunk = 8 rows x 64 cols = 1 KB = one wave-wide global_load_lds.
  // Each wave loads A-chunks {wave+8t} and B-chunks {wave+8t}, t=0..1.
  const int lrow = lane >> 3;                // row within chunk
  const int lsw = ((lane & 7) ^ lrow) * 8;   // swizzled source col (elems)

  auto stageP = [&](const unsigned short* __restrict__ A,
                    const unsigned short* __restrict__ B, unsigned short* As,
                    unsigned short* Bs, int k0) {
#define GLL(src, dst)                                                        \
  __builtin_amdgcn_global_load_lds(                                          \
      (const __attribute__((address_space(1))) void*)(src),                  \
      (__attribute__((address_space(3))) void*)(dst), 16, 0, 0)
#pragma unroll
    for (int t = 0; t < 2; t++) {
      int ch = wave + 8 * t;
      GLL(A + (size_t)(m0 + 8 * ch + lrow) * K + lsw + k0, As + ch * 512);
      GLL(B + (size_t)(n0 + 8 * ch + lrow) * K + lsw + k0, Bs + ch * 512);
    }
#undef GLL
  };

  f32x4 accE[4][2], accO[4][2];
#pragma unroll
  for (int i = 0; i < 4; i++)
#pragma unroll
    for (int j = 0; j < 2; j++) {
      accE[i][j] = f32x4{0.f, 0.f, 0.f, 0.f};
      accO[i][j] = f32x4{0.f, 0.f, 0.f, 0.f};
    }

  // one parity: 12 frag reads, counted-lgkm, 2x8 MFMA under setprio
  auto parity = [&](const unsigned short* As, const unsigned short* Bs,
                    f32x4 (&acc)[4][2]) {
    const int so0 = swz;
    const int so1 = swz ^ 32;
    bf16x8 a0[4], b0[2], a1[4], b1[2];
#pragma unroll
    for (int i = 0; i < 4; i++)
      a0[i] = *(const bf16x8*)(As + (wm + i * 16 + l16) * 64 + so0);
#pragma unroll
    for (int j = 0; j < 2; j++)
      b0[j] = *(const bf16x8*)(Bs + (wn + j * 16 + l16) * 64 + so0);
#pragma unroll
    for (int i = 0; i < 4; i++)
      a1[i] = *(const bf16x8*)(As + (wm + i * 16 + l16) * 64 + so1);
#pragma unroll
    for (int j = 0; j < 2; j++)
      b1[j] = *(const bf16x8*)(Bs + (wn + j * 16 + l16) * 64 + so1);
    LGKM6();  // oldest 6 = h0 frags landed
    __builtin_amdgcn_s_setprio(1);
#pragma unroll
    for (int i = 0; i < 4; i++)
#pragma unroll
      for (int j = 0; j < 2; j++)
        acc[i][j] = __builtin_amdgcn_mfma_f32_16x16x32_bf16(
            a0[i], b0[j], acc[i][j], 0, 0, 0);
    __builtin_amdgcn_s_setprio(0);
    LGKM0();  // h1 frags landed
    __builtin_amdgcn_s_setprio(1);
#pragma unroll
    for (int i = 0; i < 4; i++)
#pragma unroll
      for (int j = 0; j < 2; j++)
        acc[i][j] = __builtin_amdgcn_mfma_f32_16x16x32_bf16(
            a1[i], b1[j], acc[i][j], 0, 0, 0);
    __builtin_amdgcn_s_setprio(0);
  };

  // prologue: E(0) in flight (4/wave)
  stageP(Ae, Be, AsE, BsE, 0);

  // loop invariant at entry: E(k0) in flight (4/wave), O-buffers free.
  for (int k0 = 0; k0 < K; k0 += 64) {
    const bool lastIt = (k0 + 64 >= K);

    stageP(Ao, Bo, AsO, BsO, k0);  // 4 loads; 8 in flight
    VMCNT4();                      // oldest 4 = E(k0) landed (own)
    BAR();                         // E(k0) landed collectively
    parity(AsE, BsE, accE);
    BAR();                         // all waves' E reads done -> E bufs free

    if (!lastIt) {
      stageP(Ae, Be, AsE, BsE, k0 + 64);  // 4 loads; 8 in flight
      VMCNT4();                           // oldest 4 = O(k0) landed (own)
    } else {
      VMCNT0();                           // drain O(k0)
    }
    BAR();                         // O(k0) landed collectively
    parity(AsO, BsO, accO);
    BAR();                         // all waves' O reads done -> O bufs free
  }

  // epilogue: D row = quad*4 + reg, col = lane&15; butterfly E/O in fp32
#pragma unroll
  for (int i = 0; i < 4; i++) {
#pragma unroll
    for (int j = 0; j < 2; j++) {
      int n = n0 + wn + j * 16 + l16;
      int mb = m0 + wm + i * 16 + quad * 4;
#pragma unroll
      for (int r = 0; r < 4; r++) {
        float e = accE[i][j][r];
        float o = accO[i][j][r];
        int m = mb + r;
        if (STAGE == 1) {
          unsigned short* mat = (n & 1) ? out1 : out0;
          int c = n >> 1;
          mat[(size_t)m * outStride + c] = f2bf(e + o);
          mat[(size_t)(Lfull - 1 - m) * outStride + c] = f2bf(e - o);
        } else {
          float* y = (float*)out0;
          y[(size_t)m * outStride + n] = e + o;
          y[(size_t)(Lfull - 1 - m) * outStride + n] = o - e;
        }
      }
    }
  }
}

extern "C" void kernel_launch(void* const* d_in, const int* in_sizes, int n_in,
                              void* d_out, int out_size, void* d_ws,
                              size_t ws_size, hipStream_t stream) {
  const float* x = (const float*)d_in[0];
  const int M = in_sizes[1] / 2;  // expkM is [M,2]
  const int N = in_sizes[2] / 2;  // expkN is [N,2]
  const size_t MN = (size_t)M * N;

  // workspace (u16 units), 3*MN u16 = 96 MB @4096:
  //  [0, MN/2)      xe  [M x N/2]
  //  [MN/2, MN)     xo  [M x N/2]
  //  [MN, 5MN/4)    Ce ; [5MN/4, 3MN/2) Co     [N/2 x N/2]
  //  [3MN/2, 7MN/4) Se ; [7MN/4, 2MN)   So     [M/2 x M/2]
  //  [2MN, 5MN/2)   tTe [N x M/2]
  //  [5MN/2, 3MN)   tTo [N x M/2]
  unsigned short* ws = (unsigned short*)d_ws;
  unsigned short* xe = ws;
  unsigned short* xo = ws + MN / 2;
  unsigned short* Ce = ws + MN;
  unsigned short* Co = ws + MN + MN / 4;
  unsigned short* Se = ws + MN * 3 / 2;
  unsigned short* So = ws + MN * 7 / 4;
  unsigned short* tTe = ws + MN * 2;
  unsigned short* tTo = ws + MN * 5 / 2;

  int shiftN = 0; while ((1 << shiftN) < N) shiftN++;
  int shiftM = 0; while ((1 << shiftM) < M) shiftM++;

  // 1: fused prep — convert+deint, gen Ce/Co, gen Se/So
  int nConvBlocks = (int)(MN / 16 / 256);
  int nGenNBlocks = (N / 2) * (N / 2) / 8 / 256;
  int nGenMBlocks = (M / 2) * (M / 2) / 8 / 256;
  prep_kernel<<<nConvBlocks + nGenNBlocks + nGenMBlocks, 256, 0, stream>>>(
      (const f32x4*)x, (u16x8*)xe, (u16x8*)xo, (u16x8*)Ce, (u16x8*)Co,
      (u16x8*)Se, (u16x8*)So, nConvBlocks, nGenNBlocks, shiftN - 4,
      (N / 16) - 1, (unsigned)(4 * N - 1),
      (float)(3.14159265358979323846 / (2.0 * N)), shiftM - 4, (M / 16) - 1,
      (unsigned)(4 * M - 1), (float)(3.14159265358979323846 / (2.0 * M)));

  // 2: F1 — E/O GEMMs (K=N/2) + v-butterfly + p-parity deint -> tTe/tTo
  //    grid: x over p (M/128), y over v' ((N/2)/128); 512 threads
  fused_gemm_kernel<1><<<dim3(M / 128, (N / 2) / 128), 512, 0, stream>>>(
      Ce, Co, xe, xo, tTe, tTo, M / 2, N / 2, N);

  // 3: F2 — E/O GEMMs (K=M/2) + u-butterfly -> y fp32
  //    grid: x over v (N/128), y over u' ((M/2)/128); 512 threads
  fused_gemm_kernel<2><<<dim3(N / 128, (M / 2) / 128), 512, 0, stream>>>(
      Se, So, tTe, tTo, (unsigned short*)d_out, nullptr, N, M / 2, M);
}

// Round 9
// 267.763 us; speedup vs baseline: 1.1861x; 1.1861x over previous
//
#include <hip/hip_runtime.h>
#include <hip/hip_bf16.h>
#include <stdint.h>
#include <cmath>

// IDXST_IDCT on MI355X: y = S · x · C^T with
//   C[v,q] = cos(pi*q*(2v+1)/(2N)),  S[u,p] = sin(pi*p*(2u+1)/(2M))
// Butterfly halves GEMM FLOPs (dual E/O accumulators, fused epilogue).
// R15 = R10 (best: 79.3us/GEMM) + two independently-verified micro-levers:
//  (a) 8x8 XCD supertile swizzle (R14-measured: FETCH 140->98 MB, -30%);
//  (b) unpinned mid-parity lgkm (R10's LGKM6/LGKM0+sched_barrier pins
//      blocked compiler read/MFMA interleave — m141/m97 evidence). One
//      LGKM0 retained before each buffer-freeing BAR (WAR safety: s_barrier
//      doesn't drain lgkm; compiler may sink reg-only MFMAs past it, #18).
// Geometry unchanged: BM=BN=128, BK=64, 256 thr (4 waves of 64x64),
// 64 KB LDS, 2 blocks/CU; counted vmcnt(4)/wave never drained mid-loop.
// K-order/acc chain bit-identical to R10 -> absmax must stay 64.0.
// R11..R14 lessons encoded: staging granule = full 128-B rows only;
// square wave tiles only; no deep reg-prefetch (spills); no 1-block/CU.
// 3 dispatches total: prep, F1 (GEMM+bfly1+deint), F2 (GEMM+bfly2).

typedef __attribute__((ext_vector_type(4))) float f32x4;
typedef __attribute__((ext_vector_type(8))) unsigned short u16x8;
typedef __attribute__((ext_vector_type(8))) __bf16 bf16x8;

__device__ __forceinline__ unsigned short f2bf(float f) {
  union { float f; unsigned u; } v; v.f = f;
  unsigned u = v.u + 0x7fffu + ((v.u >> 16) & 1u);  // RNE
  return (unsigned short)(u >> 16);
}

// ---- gen device helper: half transform matrices [L/2 x L/2] bf16 ----
__device__ __forceinline__ void gen_half(int idx, u16x8* Pe, u16x8* Po,
                                         int isSin, int jshift, int jmask,
                                         unsigned mask4L, float sc) {
  int i = idx >> jshift;           // row
  int jb = (idx & jmask) * 8;      // first col
  unsigned tp = 2u * (unsigned)i + 1u;
  unsigned re = (2u * (unsigned)jb * tp) & mask4L;
  unsigned ro = (re + tp) & mask4L;
  unsigned step = (2u * tp) & mask4L;
  u16x8 pe, po;
#pragma unroll
  for (int t = 0; t < 8; t++) {
    float se_, ce_, so_, co_;
    __sincosf((float)re * sc, &se_, &ce_);
    __sincosf((float)ro * sc, &so_, &co_);
    pe[t] = f2bf(isSin ? se_ : ce_);
    po[t] = f2bf(isSin ? so_ : co_);
    re = (re + step) & mask4L;
    ro = (ro + step) & mask4L;
  }
  Pe[idx] = pe;
  Po[idx] = po;
}

// ---- single prep dispatch: convert+deint | gen Ce/Co | gen Se/So ----
__global__ void prep_kernel(const f32x4* __restrict__ x, u16x8* __restrict__ xe,
                            u16x8* __restrict__ xo, u16x8* __restrict__ Ce,
                            u16x8* __restrict__ Co, u16x8* __restrict__ Se,
                            u16x8* __restrict__ So, int nConvBlocks,
                            int nGenNBlocks, int jshiftN, int jmaskN,
                            unsigned mask4N, float scN, int jshiftM, int jmaskM,
                            unsigned mask4M, float scM) {
  int b = blockIdx.x;
  if (b < nConvBlocks) {
    int idx = b * 256 + threadIdx.x;
    f32x4 a = x[4 * idx], bb = x[4 * idx + 1], c = x[4 * idx + 2],
          d = x[4 * idx + 3];
    u16x8 e, o;
    e[0] = f2bf(a[0]);  o[0] = f2bf(a[1]);  e[1] = f2bf(a[2]);  o[1] = f2bf(a[3]);
    e[2] = f2bf(bb[0]); o[2] = f2bf(bb[1]); e[3] = f2bf(bb[2]); o[3] = f2bf(bb[3]);
    e[4] = f2bf(c[0]);  o[4] = f2bf(c[1]);  e[5] = f2bf(c[2]);  o[5] = f2bf(c[3]);
    e[6] = f2bf(d[0]);  o[6] = f2bf(d[1]);  e[7] = f2bf(d[2]);  o[7] = f2bf(d[3]);
    xe[idx] = e;
    xo[idx] = o;
  } else if (b < nConvBlocks + nGenNBlocks) {
    int idx = (b - nConvBlocks) * 256 + threadIdx.x;
    gen_half(idx, Ce, Co, 0, jshiftN, jmaskN, mask4N, scN);
  } else {
    int idx = (b - nConvBlocks - nGenNBlocks) * 256 + threadIdx.x;
    gen_half(idx, Se, So, 1, jshiftM, jmaskM, mask4M, scM);
  }
}

#define LGKM0()                                             \
  do {                                                      \
    asm volatile("s_waitcnt lgkmcnt(0)" ::: "memory");      \
    __builtin_amdgcn_sched_barrier(0);                      \
  } while (0)
#define VMCNT4()                                            \
  do {                                                      \
    asm volatile("s_waitcnt vmcnt(4)" ::: "memory");        \
    __builtin_amdgcn_sched_barrier(0);                      \
  } while (0)
#define VMCNT0()                                            \
  do {                                                      \
    asm volatile("s_waitcnt vmcnt(0)" ::: "memory");        \
    __builtin_amdgcn_sched_barrier(0);                      \
  } while (0)
#define BAR() __builtin_amdgcn_s_barrier()

// ---- fused dual bt-GEMM + butterfly epilogue, counted-wait pipeline ----
// accE[m,n] = sum_k Ae[m,k]*Be[n,k]; accO likewise with Ao/Bo.
// BM=BN=128, BK=64, 256 threads (4 waves of 64x64; 2m x 2n), 2 blocks/CU.
// LDS: elem (row,col) at row*64 + ((col/8)^(row&7))*8 + col%8; staging lane l
// sources global col ((l&7)^(l>>3))*8 so dst stays wave-uniform-base+lane*16.
// STAGE==1 (m=v, n=p): (p&1?out1:out0)[v, p>>1] = E+O;
//                      [...][Lfull-1-v, p>>1]   = E-O   (bf16)
// STAGE==2 (m=u, n=v): y[u,v] = E+O; y[Lfull-1-u,v] = O-E  (fp32, out0)
template <int STAGE>
__global__ __launch_bounds__(256, 2) void fused_gemm_kernel(
    const unsigned short* __restrict__ Ae,
    const unsigned short* __restrict__ Ao,
    const unsigned short* __restrict__ Be,
    const unsigned short* __restrict__ Bo,
    unsigned short* __restrict__ out0, unsigned short* __restrict__ out1,
    int outStride, int K, int Lfull) {
  __shared__ unsigned short AsE[128 * 64];
  __shared__ unsigned short BsE[128 * 64];
  __shared__ unsigned short AsO[128 * 64];
  __shared__ unsigned short BsO[128 * 64];

  const int tid = threadIdx.x;

  // XCD-aware swizzle. Preferred: 8x8 block supertiles per XCD (R14:
  // FETCH 140->98 MB). Requires gx%8==0, gy%8==0, (gx/8)*(gy/8)==8
  // (true for our 32x16 grids). Fallback: bijective strip swizzle.
  int bx = blockIdx.x, by = blockIdx.y;
  {
    const int gx = gridDim.x, gy = gridDim.y;
    const int lin = by * gx + bx;
    if ((gx % 8) == 0 && (gy % 8) == 0 && ((gx >> 3) * (gy >> 3)) == 8) {
      const int xcd = lin & 7, idx = lin >> 3;
      const int spx = gx >> 3;  // supertiles along x
      const int sx = xcd % spx, sy = xcd / spx;
      bx = sx * 8 + (idx & 7);
      by = sy * 8 + (idx >> 3);
    } else {
      const int nwg = gx * gy;
      if ((nwg & 7) == 0) {
        const int swb = (lin & 7) * (nwg >> 3) + (lin >> 3);
        bx = swb % gx;
        by = swb / gx;
      }
    }
  }
  const int m0 = by * 128;
  const int n0 = bx * 128;

  const int wave = tid >> 6;
  const int lane = tid & 63;
  const int wm = (wave & 1) * 64;   // 2 m-waves
  const int wn = (wave >> 1) * 64;  // 2 n-waves
  const int l16 = lane & 15;
  const int quad = lane >> 4;
  const int swz = (quad ^ (l16 & 7)) * 8;  // frag col swizzle, k-half 0

  // staging: chunk = 8 rows x 64 cols = 1 KB = one wave-wide global_load_lds.
  // Each wave loads A-chunks {wave+4t} and B-chunks {wave+4t}, t=0..3.
  const int lrow = lane >> 3;                // row within chunk
  const int lsw = ((lane & 7) ^ lrow) * 8;   // swizzled source col (elems)

  auto stageP = [&](const unsigned short* __restrict__ A,
                    const unsigned short* __restrict__ B, unsigned short* As,
                    unsigned short* Bs, int k0) {
#define GLL(src, dst)                                                        \
  __builtin_amdgcn_global_load_lds(                                          \
      (const __attribute__((address_space(1))) void*)(src),                  \
      (__attribute__((address_space(3))) void*)(dst), 16, 0, 0)
#pragma unroll
    for (int t = 0; t < 4; t++) {
      int ch = wave + 4 * t;
      GLL(A + (size_t)(m0 + 8 * ch + lrow) * K + lsw + k0, As + ch * 512);
      GLL(B + (size_t)(n0 + 8 * ch + lrow) * K + lsw + k0, Bs + ch * 512);
    }
#undef GLL
  };

  f32x4 accE[4][4], accO[4][4];
#pragma unroll
  for (int i = 0; i < 4; i++)
#pragma unroll
    for (int j = 0; j < 4; j++) {
      accE[i][j] = f32x4{0.f, 0.f, 0.f, 0.f};
      accO[i][j] = f32x4{0.f, 0.f, 0.f, 0.f};
    }

  // one parity: 16 frag reads + 32 MFMA, compiler-scheduled lgkm
  // (no inline lgkm pins inside — m141/m97: compiler emits fine-grained
  // lgkmcnt itself and may interleave reads with MFMAs).
  auto parity = [&](const unsigned short* As, const unsigned short* Bs,
                    f32x4 (&acc)[4][4]) {
    const int so0 = swz;
    const int so1 = swz ^ 32;
    bf16x8 a0[4], b0[4], a1[4], b1[4];
#pragma unroll
    for (int i = 0; i < 4; i++)
      a0[i] = *(const bf16x8*)(As + (wm + i * 16 + l16) * 64 + so0);
#pragma unroll
    for (int j = 0; j < 4; j++)
      b0[j] = *(const bf16x8*)(Bs + (wn + j * 16 + l16) * 64 + so0);
    __builtin_amdgcn_s_setprio(1);
#pragma unroll
    for (int i = 0; i < 4; i++)
#pragma unroll
      for (int j = 0; j < 4; j++)
        acc[i][j] = __builtin_amdgcn_mfma_f32_16x16x32_bf16(
            a0[i], b0[j], acc[i][j], 0, 0, 0);
    __builtin_amdgcn_s_setprio(0);
#pragma unroll
    for (int i = 0; i < 4; i++)
      a1[i] = *(const bf16x8*)(As + (wm + i * 16 + l16) * 64 + so1);
#pragma unroll
    for (int j = 0; j < 4; j++)
      b1[j] = *(const bf16x8*)(Bs + (wn + j * 16 + l16) * 64 + so1);
    __builtin_amdgcn_s_setprio(1);
#pragma unroll
    for (int i = 0; i < 4; i++)
#pragma unroll
      for (int j = 0; j < 4; j++)
        acc[i][j] = __builtin_amdgcn_mfma_f32_16x16x32_bf16(
            a1[i], b1[j], acc[i][j], 0, 0, 0);
    __builtin_amdgcn_s_setprio(0);
  };

  // prologue: E(0) in flight (4/wave)
  stageP(Ae, Be, AsE, BsE, 0);

  // loop invariant at entry: E(k0) in flight (4/wave), O-buffers free.
  for (int k0 = 0; k0 < K; k0 += 64) {
    const bool lastIt = (k0 + 64 >= K);

    stageP(Ao, Bo, AsO, BsO, k0);  // 4 loads; 8 in flight
    VMCNT4();                      // oldest 4 = E(k0) landed (own)
    BAR();                         // E(k0) landed collectively
    parity(AsE, BsE, accE);
    LGKM0();                       // all my E reads retired (WAR safety)
    BAR();                         // all waves' E reads done -> E bufs free

    if (!lastIt) {
      stageP(Ae, Be, AsE, BsE, k0 + 64);  // 4 loads; 8 in flight
      VMCNT4();                           // oldest 4 = O(k0) landed (own)
    } else {
      VMCNT0();                           // drain O(k0)
    }
    BAR();                         // O(k0) landed collectively
    parity(AsO, BsO, accO);
    LGKM0();                       // all my O reads retired (WAR safety)
    BAR();                         // all waves' O reads done -> O bufs free
  }

  // epilogue: D row = quad*4 + reg, col = lane&15; butterfly E/O in fp32
#pragma unroll
  for (int i = 0; i < 4; i++) {
#pragma unroll
    for (int j = 0; j < 4; j++) {
      int n = n0 + wn + j * 16 + l16;
      int mb = m0 + wm + i * 16 + quad * 4;
#pragma unroll
      for (int r = 0; r < 4; r++) {
        float e = accE[i][j][r];
        float o = accO[i][j][r];
        int m = mb + r;
        if (STAGE == 1) {
          unsigned short* mat = (n & 1) ? out1 : out0;
          int c = n >> 1;
          mat[(size_t)m * outStride + c] = f2bf(e + o);
          mat[(size_t)(Lfull - 1 - m) * outStride + c] = f2bf(e - o);
        } else {
          float* y = (float*)out0;
          y[(size_t)m * outStride + n] = e + o;
          y[(size_t)(Lfull - 1 - m) * outStride + n] = o - e;
        }
      }
    }
  }
}

extern "C" void kernel_launch(void* const* d_in, const int* in_sizes, int n_in,
                              void* d_out, int out_size, void* d_ws,
                              size_t ws_size, hipStream_t stream) {
  const float* x = (const float*)d_in[0];
  const int M = in_sizes[1] / 2;  // expkM is [M,2]
  const int N = in_sizes[2] / 2;  // expkN is [N,2]
  const size_t MN = (size_t)M * N;

  // workspace (u16 units), 3*MN u16 = 96 MB @4096:
  //  [0, MN/2)      xe  [M x N/2]
  //  [MN/2, MN)     xo  [M x N/2]
  //  [MN, 5MN/4)    Ce ; [5MN/4, 3MN/2) Co     [N/2 x N/2]
  //  [3MN/2, 7MN/4) Se ; [7MN/4, 2MN)   So     [M/2 x M/2]
  //  [2MN, 5MN/2)   tTe [N x M/2]
  //  [5MN/2, 3MN)   tTo [N x M/2]
  unsigned short* ws = (unsigned short*)d_ws;
  unsigned short* xe = ws;
  unsigned short* xo = ws + MN / 2;
  unsigned short* Ce = ws + MN;
  unsigned short* Co = ws + MN + MN / 4;
  unsigned short* Se = ws + MN * 3 / 2;
  unsigned short* So = ws + MN * 7 / 4;
  unsigned short* tTe = ws + MN * 2;
  unsigned short* tTo = ws + MN * 5 / 2;

  int shiftN = 0; while ((1 << shiftN) < N) shiftN++;
  int shiftM = 0; while ((1 << shiftM) < M) shiftM++;

  // 1: fused prep — convert+deint, gen Ce/Co, gen Se/So
  int nConvBlocks = (int)(MN / 16 / 256);
  int nGenNBlocks = (N / 2) * (N / 2) / 8 / 256;
  int nGenMBlocks = (M / 2) * (M / 2) / 8 / 256;
  prep_kernel<<<nConvBlocks + nGenNBlocks + nGenMBlocks, 256, 0, stream>>>(
      (const f32x4*)x, (u16x8*)xe, (u16x8*)xo, (u16x8*)Ce, (u16x8*)Co,
      (u16x8*)Se, (u16x8*)So, nConvBlocks, nGenNBlocks, shiftN - 4,
      (N / 16) - 1, (unsigned)(4 * N - 1),
      (float)(3.14159265358979323846 / (2.0 * N)), shiftM - 4, (M / 16) - 1,
      (unsigned)(4 * M - 1), (float)(3.14159265358979323846 / (2.0 * M)));

  // 2: F1 — E/O GEMMs (K=N/2) + v-butterfly + p-parity deint -> tTe/tTo
  //    grid: x over p (M/128), y over v' ((N/2)/128); 256 threads
  fused_gemm_kernel<1><<<dim3(M / 128, (N / 2) / 128), 256, 0, stream>>>(
      Ce, Co, xe, xo, tTe, tTo, M / 2, N / 2, N);

  // 3: F2 — E/O GEMMs (K=M/2) + u-butterfly -> y fp32
  //    grid: x over v (N/128), y over u' ((M/2)/128); 256 threads
  fused_gemm_kernel<2><<<dim3(N / 128, (M / 2) / 128), 256, 0, stream>>>(
      Se, So, tTe, tTo, (unsigned short*)d_out, nullptr, N, M / 2, M);
}

// Round 10
// 260.234 us; speedup vs baseline: 1.2204x; 1.0289x over previous
//
#include <hip/hip_runtime.h>
#include <hip/hip_bf16.h>
#include <stdint.h>
#include <cmath>

// IDXST_IDCT on MI355X: y = S · x · C^T with
//   C[v,q] = cos(pi*q*(2v+1)/(2N)),  S[u,p] = sin(pi*p*(2u+1)/(2M))
// Butterfly halves GEMM FLOPs (dual E/O accumulators, fused epilogue).
// R16 = R10 exact (best structure: pinned parity LGKM8/LGKM0, VMCNT8
// counted waits, BM=BN=128 BK=64, 4 waves of 64x64, 64KB LDS, 2 blocks/CU)
//  + R14's verified 8x8 XCD supertile swizzle (FETCH 140->66 MB)
//  + NEW: anti-phase stagger. Measured R10/R15: iter = 6190 cyc =
//    MFMA(2480/SIMD) + LDS(3600/CU) SERIAL SUM -> the two co-resident
//    blocks per CU run in phase (same start time, identical period, no
//    interaction -> phase offset conserved) so MFMA and LDS windows never
//    overlap. Fix: blocks with lin >= nwg/2 (the second resident on each
//    CU) sleep ~1900 cyc once at entry -> anti-phase -> block A's MFMA
//    burst covers block B's LDS burst. Zero numeric change.
// R11-R15 lessons: staging granule = full 128-B rows; square wave tiles;
// no deep reg-prefetch (spills); no 1-block/CU lockstep; VMCNT must equal
// own in-flight count (R15's VMCNT4 over-waited).
// K-order/acc chain bit-identical to R10 -> absmax must stay 64.0.
// 3 dispatches total: prep, F1 (GEMM+bfly1+deint), F2 (GEMM+bfly2).

typedef __attribute__((ext_vector_type(4))) float f32x4;
typedef __attribute__((ext_vector_type(8))) unsigned short u16x8;
typedef __attribute__((ext_vector_type(8))) __bf16 bf16x8;

__device__ __forceinline__ unsigned short f2bf(float f) {
  union { float f; unsigned u; } v; v.f = f;
  unsigned u = v.u + 0x7fffu + ((v.u >> 16) & 1u);  // RNE
  return (unsigned short)(u >> 16);
}

// ---- gen device helper: half transform matrices [L/2 x L/2] bf16 ----
__device__ __forceinline__ void gen_half(int idx, u16x8* Pe, u16x8* Po,
                                         int isSin, int jshift, int jmask,
                                         unsigned mask4L, float sc) {
  int i = idx >> jshift;           // row
  int jb = (idx & jmask) * 8;      // first col
  unsigned tp = 2u * (unsigned)i + 1u;
  unsigned re = (2u * (unsigned)jb * tp) & mask4L;
  unsigned ro = (re + tp) & mask4L;
  unsigned step = (2u * tp) & mask4L;
  u16x8 pe, po;
#pragma unroll
  for (int t = 0; t < 8; t++) {
    float se_, ce_, so_, co_;
    __sincosf((float)re * sc, &se_, &ce_);
    __sincosf((float)ro * sc, &so_, &co_);
    pe[t] = f2bf(isSin ? se_ : ce_);
    po[t] = f2bf(isSin ? so_ : co_);
    re = (re + step) & mask4L;
    ro = (ro + step) & mask4L;
  }
  Pe[idx] = pe;
  Po[idx] = po;
}

// ---- single prep dispatch: convert+deint | gen Ce/Co | gen Se/So ----
__global__ void prep_kernel(const f32x4* __restrict__ x, u16x8* __restrict__ xe,
                            u16x8* __restrict__ xo, u16x8* __restrict__ Ce,
                            u16x8* __restrict__ Co, u16x8* __restrict__ Se,
                            u16x8* __restrict__ So, int nConvBlocks,
                            int nGenNBlocks, int jshiftN, int jmaskN,
                            unsigned mask4N, float scN, int jshiftM, int jmaskM,
                            unsigned mask4M, float scM) {
  int b = blockIdx.x;
  if (b < nConvBlocks) {
    int idx = b * 256 + threadIdx.x;
    f32x4 a = x[4 * idx], bb = x[4 * idx + 1], c = x[4 * idx + 2],
          d = x[4 * idx + 3];
    u16x8 e, o;
    e[0] = f2bf(a[0]);  o[0] = f2bf(a[1]);  e[1] = f2bf(a[2]);  o[1] = f2bf(a[3]);
    e[2] = f2bf(bb[0]); o[2] = f2bf(bb[1]); e[3] = f2bf(bb[2]); o[3] = f2bf(bb[3]);
    e[4] = f2bf(c[0]);  o[4] = f2bf(c[1]);  e[5] = f2bf(c[2]);  o[5] = f2bf(c[3]);
    e[6] = f2bf(d[0]);  o[6] = f2bf(d[1]);  e[7] = f2bf(d[2]);  o[7] = f2bf(d[3]);
    xe[idx] = e;
    xo[idx] = o;
  } else if (b < nConvBlocks + nGenNBlocks) {
    int idx = (b - nConvBlocks) * 256 + threadIdx.x;
    gen_half(idx, Ce, Co, 0, jshiftN, jmaskN, mask4N, scN);
  } else {
    int idx = (b - nConvBlocks - nGenNBlocks) * 256 + threadIdx.x;
    gen_half(idx, Se, So, 1, jshiftM, jmaskM, mask4M, scM);
  }
}

#define LGKM8()                                             \
  do {                                                      \
    asm volatile("s_waitcnt lgkmcnt(8)" ::: "memory");      \
    __builtin_amdgcn_sched_barrier(0);                      \
  } while (0)
#define LGKM0()                                             \
  do {                                                      \
    asm volatile("s_waitcnt lgkmcnt(0)" ::: "memory");      \
    __builtin_amdgcn_sched_barrier(0);                      \
  } while (0)
#define VMCNT8()                                            \
  do {                                                      \
    asm volatile("s_waitcnt vmcnt(8)" ::: "memory");        \
    __builtin_amdgcn_sched_barrier(0);                      \
  } while (0)
#define VMCNT0()                                            \
  do {                                                      \
    asm volatile("s_waitcnt vmcnt(0)" ::: "memory");        \
    __builtin_amdgcn_sched_barrier(0);                      \
  } while (0)
#define BAR() __builtin_amdgcn_s_barrier()

// ---- fused dual bt-GEMM + butterfly epilogue, counted-wait pipeline ----
// accE[m,n] = sum_k Ae[m,k]*Be[n,k]; accO likewise with Ao/Bo.
// BM=BN=128, BK=64, 256 threads (4 waves of 64x64; 2m x 2n), 2 blocks/CU.
// LDS: elem (row,col) at row*64 + ((col/8)^(row&7))*8 + col%8; staging lane l
// sources global col ((l&7)^(l>>3))*8 so dst stays wave-uniform-base+lane*16.
// STAGE==1 (m=v, n=p): (p&1?out1:out0)[v, p>>1] = E+O;
//                      [...][Lfull-1-v, p>>1]   = E-O   (bf16)
// STAGE==2 (m=u, n=v): y[u,v] = E+O; y[Lfull-1-u,v] = O-E  (fp32, out0)
template <int STAGE>
__global__ __launch_bounds__(256, 2) void fused_gemm_kernel(
    const unsigned short* __restrict__ Ae,
    const unsigned short* __restrict__ Ao,
    const unsigned short* __restrict__ Be,
    const unsigned short* __restrict__ Bo,
    unsigned short* __restrict__ out0, unsigned short* __restrict__ out1,
    int outStride, int K, int Lfull) {
  __shared__ unsigned short AsE[128 * 64];
  __shared__ unsigned short BsE[128 * 64];
  __shared__ unsigned short AsO[128 * 64];
  __shared__ unsigned short BsO[128 * 64];

  const int tid = threadIdx.x;

  // XCD-aware swizzle: 8x8 block supertiles per XCD (R14/R15: FETCH
  // 140->66 MB). Requires gx%8==0, gy%8==0, (gx/8)*(gy/8)==8 (true for
  // our 32x16 grids). Fallback: bijective strip swizzle.
  const int gx = gridDim.x, gy = gridDim.y;
  const int lin = blockIdx.y * gx + blockIdx.x;
  int bx = blockIdx.x, by = blockIdx.y;
  {
    if ((gx % 8) == 0 && (gy % 8) == 0 && ((gx >> 3) * (gy >> 3)) == 8) {
      const int xcd = lin & 7, idx = lin >> 3;
      const int spx = gx >> 3;  // supertiles along x
      const int sx = xcd % spx, sy = xcd / spx;
      bx = sx * 8 + (idx & 7);
      by = sy * 8 + (idx >> 3);
    } else {
      const int nwg = gx * gy;
      if ((nwg & 7) == 0) {
        const int swb = (lin & 7) * (nwg >> 3) + (lin >> 3);
        bx = swb % gx;
        by = swb / gx;
      }
    }
  }
  const int m0 = by * 128;
  const int n0 = bx * 128;

  // Anti-phase stagger: with nwg = 2x256 blocks, lin >= nwg/2 are the
  // second resident on each CU. One-time ~1900-cyc sleep puts them half
  // an LDS-window out of phase with the first resident, so the two
  // blocks' MFMA and LDS bursts interleave instead of colliding.
  if (lin >= ((gx * gy) >> 1)) {
    __builtin_amdgcn_s_sleep(15);  // ~960 cyc
    __builtin_amdgcn_s_sleep(15);  // ~960 cyc
  }

  const int wave = tid >> 6;
  const int lane = tid & 63;
  const int wm = (wave & 1) * 64;   // 2 m-waves
  const int wn = (wave >> 1) * 64;  // 2 n-waves
  const int l16 = lane & 15;
  const int quad = lane >> 4;
  const int swz = (quad ^ (l16 & 7)) * 8;  // frag col swizzle, k-half 0

  // staging: chunk = 8 rows x 64 cols = 1 KB = one wave-wide global_load_lds.
  // Each wave loads A-chunks {wave+4t} and B-chunks {wave+4t}, t=0..3.
  const int lrow = lane >> 3;                // row within chunk
  const int lsw = ((lane & 7) ^ lrow) * 8;   // swizzled source col (elems)

  auto stageP = [&](const unsigned short* __restrict__ A,
                    const unsigned short* __restrict__ B, unsigned short* As,
                    unsigned short* Bs, int k0) {
#define GLL(src, dst)                                                        \
  __builtin_amdgcn_global_load_lds(                                          \
      (const __attribute__((address_space(1))) void*)(src),                  \
      (__attribute__((address_space(3))) void*)(dst), 16, 0, 0)
#pragma unroll
    for (int t = 0; t < 4; t++) {
      int ch = wave + 4 * t;
      GLL(A + (size_t)(m0 + 8 * ch + lrow) * K + lsw + k0, As + ch * 512);
      GLL(B + (size_t)(n0 + 8 * ch + lrow) * K + lsw + k0, Bs + ch * 512);
    }
#undef GLL
  };

  f32x4 accE[4][4], accO[4][4];
#pragma unroll
  for (int i = 0; i < 4; i++)
#pragma unroll
    for (int j = 0; j < 4; j++) {
      accE[i][j] = f32x4{0.f, 0.f, 0.f, 0.f};
      accO[i][j] = f32x4{0.f, 0.f, 0.f, 0.f};
    }

  // one parity: read all 16 frags, counted-lgkm, 2x16 MFMA under setprio
  auto parity = [&](const unsigned short* As, const unsigned short* Bs,
                    f32x4 (&acc)[4][4]) {
    const int so0 = swz;
    const int so1 = swz ^ 32;
    bf16x8 a0[4], b0[4], a1[4], b1[4];
#pragma unroll
    for (int i = 0; i < 4; i++)
      a0[i] = *(const bf16x8*)(As + (wm + i * 16 + l16) * 64 + so0);
#pragma unroll
    for (int j = 0; j < 4; j++)
      b0[j] = *(const bf16x8*)(Bs + (wn + j * 16 + l16) * 64 + so0);
#pragma unroll
    for (int i = 0; i < 4; i++)
      a1[i] = *(const bf16x8*)(As + (wm + i * 16 + l16) * 64 + so1);
#pragma unroll
    for (int j = 0; j < 4; j++)
      b1[j] = *(const bf16x8*)(Bs + (wn + j * 16 + l16) * 64 + so1);
    LGKM8();  // oldest 8 = h0 frags landed
    __builtin_amdgcn_s_setprio(1);
#pragma unroll
    for (int i = 0; i < 4; i++)
#pragma unroll
      for (int j = 0; j < 4; j++)
        acc[i][j] = __builtin_amdgcn_mfma_f32_16x16x32_bf16(
            a0[i], b0[j], acc[i][j], 0, 0, 0);
    __builtin_amdgcn_s_setprio(0);
    LGKM0();  // h1 frags landed
    __builtin_amdgcn_s_setprio(1);
#pragma unroll
    for (int i = 0; i < 4; i++)
#pragma unroll
      for (int j = 0; j < 4; j++)
        acc[i][j] = __builtin_amdgcn_mfma_f32_16x16x32_bf16(
            a1[i], b1[j], acc[i][j], 0, 0, 0);
    __builtin_amdgcn_s_setprio(0);
  };

  // prologue: E(0) in flight (8/wave)
  stageP(Ae, Be, AsE, BsE, 0);

  // loop invariant at entry: E(k0) in flight (8/wave), O-buffers free.
  for (int k0 = 0; k0 < K; k0 += 64) {
    const bool lastIt = (k0 + 64 >= K);

    stageP(Ao, Bo, AsO, BsO, k0);  // 8 loads; 16 in flight
    VMCNT8();                      // oldest 8 = E(k0) landed (own)
    BAR();                         // E(k0) landed collectively
    parity(AsE, BsE, accE);
    BAR();                         // all waves' E reads done -> E bufs free

    if (!lastIt) {
      stageP(Ae, Be, AsE, BsE, k0 + 64);  // 8 loads; 16 in flight
      VMCNT8();                           // oldest 8 = O(k0) landed (own)
    } else {
      VMCNT0();                           // drain O(k0)
    }
    BAR();                         // O(k0) landed collectively
    parity(AsO, BsO, accO);
    BAR();                         // all waves' O reads done -> O bufs free
  }

  // epilogue: D row = quad*4 + reg, col = lane&15; butterfly E/O in fp32
#pragma unroll
  for (int i = 0; i < 4; i++) {
#pragma unroll
    for (int j = 0; j < 4; j++) {
      int n = n0 + wn + j * 16 + l16;
      int mb = m0 + wm + i * 16 + quad * 4;
#pragma unroll
      for (int r = 0; r < 4; r++) {
        float e = accE[i][j][r];
        float o = accO[i][j][r];
        int m = mb + r;
        if (STAGE == 1) {
          unsigned short* mat = (n & 1) ? out1 : out0;
          int c = n >> 1;
          mat[(size_t)m * outStride + c] = f2bf(e + o);
          mat[(size_t)(Lfull - 1 - m) * outStride + c] = f2bf(e - o);
        } else {
          float* y = (float*)out0;
          y[(size_t)m * outStride + n] = e + o;
          y[(size_t)(Lfull - 1 - m) * outStride + n] = o - e;
        }
      }
    }
  }
}

extern "C" void kernel_launch(void* const* d_in, const int* in_sizes, int n_in,
                              void* d_out, int out_size, void* d_ws,
                              size_t ws_size, hipStream_t stream) {
  const float* x = (const float*)d_in[0];
  const int M = in_sizes[1] / 2;  // expkM is [M,2]
  const int N = in_sizes[2] / 2;  // expkN is [N,2]
  const size_t MN = (size_t)M * N;

  // workspace (u16 units), 3*MN u16 = 96 MB @4096:
  //  [0, MN/2)      xe  [M x N/2]
  //  [MN/2, MN)     xo  [M x N/2]
  //  [MN, 5MN/4)    Ce ; [5MN/4, 3MN/2) Co     [N/2 x N/2]
  //  [3MN/2, 7MN/4) Se ; [7MN/4, 2MN)   So     [M/2 x M/2]
  //  [2MN, 5MN/2)   tTe [N x M/2]
  //  [5MN/2, 3MN)   tTo [N x M/2]
  unsigned short* ws = (unsigned short*)d_ws;
  unsigned short* xe = ws;
  unsigned short* xo = ws + MN / 2;
  unsigned short* Ce = ws + MN;
  unsigned short* Co = ws + MN + MN / 4;
  unsigned short* Se = ws + MN * 3 / 2;
  unsigned short* So = ws + MN * 7 / 4;
  unsigned short* tTe = ws + MN * 2;
  unsigned short* tTo = ws + MN * 5 / 2;

  int shiftN = 0; while ((1 << shiftN) < N) shiftN++;
  int shiftM = 0; while ((1 << shiftM) < M) shiftM++;

  // 1: fused prep — convert+deint, gen Ce/Co, gen Se/So
  int nConvBlocks = (int)(MN / 16 / 256);
  int nGenNBlocks = (N / 2) * (N / 2) / 8 / 256;
  int nGenMBlocks = (M / 2) * (M / 2) / 8 / 256;
  prep_kernel<<<nConvBlocks + nGenNBlocks + nGenMBlocks, 256, 0, stream>>>(
      (const f32x4*)x, (u16x8*)xe, (u16x8*)xo, (u16x8*)Ce, (u16x8*)Co,
      (u16x8*)Se, (u16x8*)So, nConvBlocks, nGenNBlocks, shiftN - 4,
      (N / 16) - 1, (unsigned)(4 * N - 1),
      (float)(3.14159265358979323846 / (2.0 * N)), shiftM - 4, (M / 16) - 1,
      (unsigned)(4 * M - 1), (float)(3.14159265358979323846 / (2.0 * M)));

  // 2: F1 — E/O GEMMs (K=N/2) + v-butterfly + p-parity deint -> tTe/tTo
  //    grid: x over p (M/128), y over v' ((N/2)/128); 256 threads
  fused_gemm_kernel<1><<<dim3(M / 128, (N / 2) / 128), 256, 0, stream>>>(
      Ce, Co, xe, xo, tTe, tTo, M / 2, N / 2, N);

  // 3: F2 — E/O GEMMs (K=M/2) + u-butterfly -> y fp32
  //    grid: x over v (N/128), y over u' ((M/2)/128); 256 threads
  fused_gemm_kernel<2><<<dim3(N / 128, (M / 2) / 128), 256, 0, stream>>>(
      Se, So, tTe, tTo, (unsigned short*)d_out, nullptr, N, M / 2, M);
}